// Round 1
// baseline (338.501 us; speedup 1.0000x reference)
//
#include <hip/hip_runtime.h>

#define BLOCK 256
#define C_DIM 10000
#define TAU 1.0f

// Monotone bijection float -> uint32 (larger float => larger key)
__device__ __forceinline__ unsigned flip_key(float f) {
    unsigned u = __float_as_uint(f);
    return (u & 0x80000000u) ? ~u : (u | 0x80000000u);
}
__device__ __forceinline__ float unflip_key(unsigned k) {
    unsigned u = (k & 0x80000000u) ? (k & 0x7fffffffu) : ~k;
    return __uint_as_float(u);
}

__global__ void zero_out_kernel(float* out, int n) {
    int i = blockIdx.x * blockDim.x + threadIdx.x;
    if (i < n) out[i] = 0.f;
}

__global__ __launch_bounds__(BLOCK) void topk_la_loss_kernel(
    const float* __restrict__ logit, const int* __restrict__ target,
    const float* __restrict__ lcn, const int* __restrict__ kpc,
    float* __restrict__ out, int B) {
    __shared__ __align__(16) unsigned keys[C_DIM];   // 40000 B
    __shared__ unsigned hist[256];
    __shared__ float red_m[4], red_s[4];
    __shared__ unsigned sh_prefix, sh_kr;
    __shared__ float sh_M, sh_Z;

    const int row = blockIdx.x;
    const int tid = threadIdx.x;
    const int lane = tid & 63;
    const int wid  = tid >> 6;
    const float* lrow = logit + (size_t)row * C_DIM;

    // ---- Pass 1: stage keys to LDS + online softmax of adj = logit + TAU*lcn
    float m = -INFINITY, s = 0.f;
    for (int j4 = tid; j4 < C_DIM / 4; j4 += BLOCK) {
        float4 f = ((const float4*)lrow)[j4];
        float4 l = ((const float4*)lcn)[j4];
        uint4 kk;
        kk.x = flip_key(f.x); kk.y = flip_key(f.y);
        kk.z = flip_key(f.z); kk.w = flip_key(f.w);
        ((uint4*)keys)[j4] = kk;
        float a;
        a = f.x + TAU * l.x;
        if (a > m) { s = s * __expf(m - a) + 1.f; m = a; } else { s += __expf(a - m); }
        a = f.y + TAU * l.y;
        if (a > m) { s = s * __expf(m - a) + 1.f; m = a; } else { s += __expf(a - m); }
        a = f.z + TAU * l.z;
        if (a > m) { s = s * __expf(m - a) + 1.f; m = a; } else { s += __expf(a - m); }
        a = f.w + TAU * l.w;
        if (a > m) { s = s * __expf(m - a) + 1.f; m = a; } else { s += __expf(a - m); }
    }
    // wave-level (m,s) combine; lane 0 of each wave holds wave result
    for (int off = 32; off > 0; off >>= 1) {
        float m2 = __shfl_down(m, off);
        float s2 = __shfl_down(s, off);
        float M2 = fmaxf(m, m2);
        s = s * __expf(m - M2) + s2 * __expf(m2 - M2);
        m = M2;
    }
    if (lane == 0) { red_m[wid] = m; red_s[wid] = s; }
    __syncthreads();
    if (tid == 0) {
        float M = red_m[0], S = red_s[0];
        for (int w = 1; w < 4; ++w) {
            float m2 = red_m[w], s2 = red_s[w];
            float M2 = fmaxf(M, m2);
            S = S * __expf(M - M2) + s2 * __expf(m2 - M2);
            M = M2;
        }
        sh_M = M; sh_Z = S;
        int t = target[row];
        int k = kpc[t];
        if (k > C_DIM) k = C_DIM;
        sh_prefix = 0u;
        sh_kr = (unsigned)k;
    }
    __syncthreads();
    const float M = sh_M;

    // ---- Radix select (MSB-first, 8-bit digits) for k-th largest key
    for (int p = 0; p < 4; ++p) {
        const int shift = 24 - 8 * p;
        const unsigned pmask = (p == 0) ? 0u : (0xFFFFFFFFu << (32 - 8 * p));
        const unsigned prefix = sh_prefix;
        hist[tid] = 0u;
        __syncthreads();
        for (int j4 = tid; j4 < C_DIM / 4; j4 += BLOCK) {
            uint4 kk = ((const uint4*)keys)[j4];
            if ((kk.x & pmask) == prefix) atomicAdd(&hist[(kk.x >> shift) & 0xFFu], 1u);
            if ((kk.y & pmask) == prefix) atomicAdd(&hist[(kk.y >> shift) & 0xFFu], 1u);
            if ((kk.z & pmask) == prefix) atomicAdd(&hist[(kk.z >> shift) & 0xFFu], 1u);
            if ((kk.w & pmask) == prefix) atomicAdd(&hist[(kk.w >> shift) & 0xFFu], 1u);
        }
        __syncthreads();
        // wave 0: suffix-sum over 256 bins (4 bins/lane) + pick the bin
        if (tid < 64) {
            unsigned h0 = hist[4 * tid + 0], h1 = hist[4 * tid + 1];
            unsigned h2 = hist[4 * tid + 2], h3 = hist[4 * tid + 3];
            unsigned loc = h0 + h1 + h2 + h3;
            unsigned suf = loc;  // will become sum over lanes >= me
            for (int off = 1; off < 64; off <<= 1) {
                unsigned o = __shfl_down(suf, off);
                if (tid + off < 64) suf += o;
            }
            unsigned sufex = suf - loc;  // sum over lanes > me (bins above my 4)
            unsigned kr = sh_kr;
            unsigned s3 = sufex + h3;
            unsigned s2 = s3 + h2;
            unsigned s1 = s2 + h1;
            unsigned s0 = s1 + h0;
            int bsel = -1; unsigned newkr = 0;
            if (s3 >= kr && s3 - h3 < kr)      { bsel = 4 * tid + 3; newkr = kr - (s3 - h3); }
            else if (s2 >= kr && s2 - h2 < kr) { bsel = 4 * tid + 2; newkr = kr - (s2 - h2); }
            else if (s1 >= kr && s1 - h1 < kr) { bsel = 4 * tid + 1; newkr = kr - (s1 - h1); }
            else if (s0 >= kr && s0 - h0 < kr) { bsel = 4 * tid + 0; newkr = kr - (s0 - h0); }
            if (bsel >= 0) {
                sh_prefix = prefix | ((unsigned)bsel << shift);
                sh_kr = newkr;
            }
        }
        __syncthreads();
    }
    const unsigned tkey = sh_prefix;  // key of the exact k-th largest logit

    // ---- Masked prob sum: sum exp(adj - M) over logit >= thresh
    float local = 0.f;
    for (int j4 = tid; j4 < C_DIM / 4; j4 += BLOCK) {
        uint4 kk = ((const uint4*)keys)[j4];
        int j = 4 * j4;
        if (kk.x >= tkey) local += __expf(unflip_key(kk.x) + TAU * lcn[j + 0] - M);
        if (kk.y >= tkey) local += __expf(unflip_key(kk.y) + TAU * lcn[j + 1] - M);
        if (kk.z >= tkey) local += __expf(unflip_key(kk.z) + TAU * lcn[j + 2] - M);
        if (kk.w >= tkey) local += __expf(unflip_key(kk.w) + TAU * lcn[j + 3] - M);
    }
    for (int off = 32; off > 0; off >>= 1) local += __shfl_down(local, off);
    if (lane == 0) red_s[wid] = local;
    __syncthreads();

    if (tid == 0) {
        float smask_exp = red_s[0] + red_s[1] + red_s[2] + red_s[3];
        float Z = sh_Z;
        int t = target[row];
        float logit_t = lrow[t];
        float adj_t = logit_t + TAU * lcn[t];
        float lpt = adj_t - M - __logf(Z);          // log_p_adj[target]
        unsigned key_t = flip_key(logit_t);
        float p_num = ((key_t >= tkey) ? __expf(lpt) : 0.f) + 1e-6f;
        float S = smask_exp / Z + (float)C_DIM * 1e-6f;
        float loss_full = -lpt;
        float loss_topk = __logf(S) - __logf(p_num);
        float loss = 0.5f * (loss_full + loss_topk);
        atomicAdd(out, loss / (float)B);
    }
}

extern "C" void kernel_launch(void* const* d_in, const int* in_sizes, int n_in,
                              void* d_out, int out_size, void* d_ws, size_t ws_size,
                              hipStream_t stream) {
    const float* logit  = (const float*)d_in[0];
    const int*   target = (const int*)d_in[1];
    const float* lcn    = (const float*)d_in[2];
    const int*   kpc    = (const int*)d_in[3];
    float* out = (float*)d_out;
    const int B = in_sizes[1];  // target is [B]

    zero_out_kernel<<<1, 64, 0, stream>>>(out, out_size);
    topk_la_loss_kernel<<<B, BLOCK, 0, stream>>>(logit, target, lcn, kpc, out, B);
}